// Round 1
// baseline (15493.936 us; speedup 1.0000x reference)
//
#include <hip/hip_runtime.h>
#include <cmath>

#define DIM    256
#define LATENT 1024
#define BATCH  128
#define SEQT   512

typedef short  short8  __attribute__((ext_vector_type(8)));
typedef float  floatx4 __attribute__((ext_vector_type(4)));

__device__ __forceinline__ short f2bf(float f) {
  union { float f; unsigned u; } v; v.f = f;
  unsigned u = v.u;
  unsigned r = (u + 0x7fffu + ((u >> 16) & 1u)) >> 16;   // RNE
  return (short)r;
}

// ---------------------------------------------------------------------------
// Kernel 1: xw[b,t,:] = x[b,t,:] @ Wx + b_in, stored to out[t][b][:] (fp32).
// M-tile 64 rows/block, A-fragments preloaded in registers, Wx slice staged
// per 64-col slice into LDS in MFMA B-fragment swizzled order.
// ---------------------------------------------------------------------------
__global__ __launch_bounds__(256) void xw_gemm(
    const float* __restrict__ x, const float* __restrict__ Win,
    const float* __restrict__ bin, float* __restrict__ out)
{
  __shared__ short lB[32 * 64 * 8];   // [(kt*4+q)=oct][c 0..63][j 0..7], 32 KB
  const int tid  = threadIdx.x;
  const int wave = tid >> 6;
  const int lane = tid & 63;
  const int q    = lane >> 4;
  const int ln   = lane & 15;
  const int m0   = blockIdx.x * 64;

  // Preload A fragments: this wave's 16 rows, all 8 K-tiles (K=256).
  short8 afr[8];
  {
    const float* xrow = x + (size_t)(m0 + wave * 16 + ln) * DIM + q * 8;
    #pragma unroll
    for (int kt = 0; kt < 8; ++kt) {
      float4 v0 = *(const float4*)(xrow + kt * 32);
      float4 v1 = *(const float4*)(xrow + kt * 32 + 4);
      short8 a;
      a[0]=f2bf(v0.x); a[1]=f2bf(v0.y); a[2]=f2bf(v0.z); a[3]=f2bf(v0.w);
      a[4]=f2bf(v1.x); a[5]=f2bf(v1.y); a[6]=f2bf(v1.z); a[7]=f2bf(v1.w);
      afr[kt] = a;
    }
  }

  for (int s = 0; s < 16; ++s) {
    __syncthreads();
    {   // stage Wx[:, s*64 .. +64) as swizzled bf16; k = oct*8 + j
      const int c  = tid & 63;
      const int o0 = tid >> 6;
      for (int oct = o0; oct < 32; oct += 4) {
        short8 w;
        #pragma unroll
        for (int j = 0; j < 8; ++j)
          w[j] = f2bf(Win[(size_t)(oct * 8 + j) * LATENT + s * 64 + c]);
        *(short8*)&lB[(oct * 64 + c) * 8] = w;
      }
    }
    __syncthreads();
    #pragma unroll
    for (int nt = 0; nt < 4; ++nt) {
      floatx4 acc0 = {0.f,0.f,0.f,0.f}, acc1 = {0.f,0.f,0.f,0.f};
      #pragma unroll
      for (int kt = 0; kt < 8; kt += 2) {
        short8 b0 = *(const short8*)&lB[(( kt   *4 + q) * 64 + nt*16 + ln) * 8];
        short8 b1 = *(const short8*)&lB[(((kt+1)*4 + q) * 64 + nt*16 + ln) * 8];
        acc0 = __builtin_amdgcn_mfma_f32_16x16x32_bf16(afr[kt],   b0, acc0, 0,0,0);
        acc1 = __builtin_amdgcn_mfma_f32_16x16x32_bf16(afr[kt+1], b1, acc1, 0,0,0);
      }
      floatx4 acc = acc0 + acc1;
      const int col = s*64 + nt*16 + ln;
      const float bv = bin[col];
      #pragma unroll
      for (int i = 0; i < 4; ++i) {
        int r = m0 + wave*16 + q*4 + i;       // flat row = b*SEQT + t
        int t = r & (SEQT - 1);
        int b = r >> 9;
        out[((size_t)t * BATCH + b) * LATENT + col] = acc[i] + bv;
      }
    }
  }
}

// ---------------------------------------------------------------------------
// Kernel 2: persistent recurrence. 512 wgs (2/CU). 8 groups x 16 batch rows;
// wg owns 16 cols of Wh in LDS. Per step: h[t-1] (bf16 ring) @ Wh-slice,
// K split across 4 waves + LDS reduce, tanh, write fp32 h to out (over xw)
// and bf16 h to ring, then release-fence + group arrival counter.
// ---------------------------------------------------------------------------
__global__ __launch_bounds__(256) void rnn_persistent(
    float* __restrict__ out, const float* __restrict__ Win,
    unsigned short* __restrict__ ring, int* __restrict__ cnt)
{
  __shared__ short lW[128 * 16 * 8];   // [(kt*4+q)][n][j], 32 KB
  __shared__ float red[4][16][16];     // 4 KB, per-wave partial C tiles

  const int tid  = threadIdx.x;
  const int wave = tid >> 6;
  const int lane = tid & 63;
  const int q    = lane >> 4;
  const int ln   = lane & 15;
  const int bid  = blockIdx.x;

  // group/col mapping: group g spread over XCD pair {g, g^1}; co-resident
  // wgs on a CU come from different groups (spin-latency hiding).
  int g, wid;
  if (bid < 256) { g = bid & 7;              wid = bid >> 3; }
  else           { int b2 = bid - 256; g = (b2 & 7) ^ 1; wid = 32 + (b2 >> 3); }
  const int col0 = wid * 16;
  const int row0 = g * 16;
  int* myflag = cnt + g * SEQT;

  // Stage Wh[:, col0..col0+16) (rows DIM..DIM+1024 of W_in) swizzled to bf16.
  for (int i = tid; i < 128 * 16; i += 256) {   // i = oct*16 + n ; k = oct*8+j
    const int oct = i >> 4, n = i & 15;
    short8 w;
    #pragma unroll
    for (int j = 0; j < 8; ++j)
      w[j] = f2bf(Win[(size_t)(DIM + oct*8 + j) * LATENT + col0 + n]);
    *(short8*)&lW[i * 8] = w;
  }

  const int erow = tid >> 4, ecol = tid & 15;
  float* outp = out + (size_t)(row0 + erow) * LATENT + col0 + ecol;
  unsigned short* ringp = ring + (size_t)(row0 + erow) * LATENT + col0 + ecol;
  __syncthreads();

  for (int t = 0; t < SEQT; ++t) {
    // xw prefetch (owner-exclusive location; issued before the spin)
    float xw = outp[(size_t)t * (BATCH * LATENT)];
    float hsum = 0.f;
    if (t > 0) {
      if (tid == 0) {
        while (__hip_atomic_load(myflag + (t-1), __ATOMIC_RELAXED,
                                 __HIP_MEMORY_SCOPE_AGENT) < 64)
          __builtin_amdgcn_s_sleep(2);
        __threadfence();   // acquire: invalidate stale L1/L2 before h reads
      }
      __syncthreads();

      // A fragments: rows row0+ln, this wave's K range, from ring slot (t-1)&3
      const unsigned short* rbase =
          ring + ((size_t)((t-1) & 3) * BATCH + row0 + ln) * LATENT
               + wave * 256 + q * 8;
      short8 a[8];
      #pragma unroll
      for (int kk = 0; kk < 8; ++kk)
        a[kk] = *(const short8*)(rbase + kk * 32);

      floatx4 acc0 = {0.f,0.f,0.f,0.f}, acc1 = {0.f,0.f,0.f,0.f};
      #pragma unroll
      for (int kk = 0; kk < 4; ++kk) {
        const int kt  = wave * 8 + kk;
        const int kt2 = wave * 8 + 4 + kk;
        short8 b  = *(const short8*)&lW[((kt  * 4 + q) * 16 + ln) * 8];
        short8 b2 = *(const short8*)&lW[((kt2 * 4 + q) * 16 + ln) * 8];
        acc0 = __builtin_amdgcn_mfma_f32_16x16x32_bf16(a[kk],     b,  acc0, 0,0,0);
        acc1 = __builtin_amdgcn_mfma_f32_16x16x32_bf16(a[4 + kk], b2, acc1, 0,0,0);
      }
      floatx4 acc = acc0 + acc1;
      #pragma unroll
      for (int i = 0; i < 4; ++i) red[wave][q*4 + i][ln] = acc[i];
      __syncthreads();
      hsum = red[0][erow][ecol] + red[1][erow][ecol]
           + red[2][erow][ecol] + red[3][erow][ecol];
    }

    const float h = tanhf(xw + hsum);
    outp [(size_t)t      * (BATCH * LATENT)] = h;                      // fp32 history (output)
    ringp[(size_t)(t & 3) * (BATCH * LATENT)] = (unsigned short)f2bf(h); // bf16 ring
    __syncthreads();
    if (tid == 0) {
      __threadfence();          // release: flush L2 so peers (any XCD) see h
      atomicAdd(myflag + t, 1);
    }
  }
}

// ---------------------------------------------------------------------------
extern "C" void kernel_launch(void* const* d_in, const int* in_sizes, int n_in,
                              void* d_out, int out_size, void* d_ws, size_t ws_size,
                              hipStream_t stream) {
  (void)in_sizes; (void)n_in; (void)out_size; (void)ws_size;
  const float* x   = (const float*)d_in[0];
  const float* Win = (const float*)d_in[1];
  const float* bin = (const float*)d_in[2];
  float* out = (float*)d_out;

  int* cnt = (int*)d_ws;                                        // 8*512 ints = 16 KB
  unsigned short* ring = (unsigned short*)((char*)d_ws + 32768); // 4*128*1024 bf16 = 1 MB

  hipMemsetAsync(cnt, 0, 8 * SEQT * sizeof(int), stream);
  xw_gemm<<<dim3(65536 / 64), dim3(256), 0, stream>>>(x, Win, bin, out);

  void* args[] = { &out, &Win, &ring, &cnt };
  hipLaunchCooperativeKernel((void*)rnn_persistent, dim3(512), dim3(256),
                             args, 0, stream);
}

// Round 2
// 5755.423 us; speedup vs baseline: 2.6921x; 2.6921x over previous
//
#include <hip/hip_runtime.h>
#include <cmath>

#define DIM    256
#define LATENT 1024
#define BATCH  128
#define SEQT   512

typedef short  short8  __attribute__((ext_vector_type(8)));
typedef float  floatx4 __attribute__((ext_vector_type(4)));
typedef unsigned long long u64;

__device__ __forceinline__ short f2bf(float f) {
  union { float f; unsigned u; } v; v.f = f;
  unsigned u = v.u;
  unsigned r = (u + 0x7fffu + ((u >> 16) & 1u)) >> 16;   // RNE
  return (short)r;
}

// ---------------------------------------------------------------------------
// Kernel 1: xw[b,t,:] = x[b,t,:] @ Wx + b_in, stored to out[t][b][:] (fp32).
// (unchanged from R1 — correct, not the bottleneck)
// ---------------------------------------------------------------------------
__global__ __launch_bounds__(256) void xw_gemm(
    const float* __restrict__ x, const float* __restrict__ Win,
    const float* __restrict__ bin, float* __restrict__ out)
{
  __shared__ short lB[32 * 64 * 8];   // [(kt*4+q)=oct][c 0..63][j 0..7], 32 KB
  const int tid  = threadIdx.x;
  const int wave = tid >> 6;
  const int lane = tid & 63;
  const int q    = lane >> 4;
  const int ln   = lane & 15;
  const int m0   = blockIdx.x * 64;

  short8 afr[8];
  {
    const float* xrow = x + (size_t)(m0 + wave * 16 + ln) * DIM + q * 8;
    #pragma unroll
    for (int kt = 0; kt < 8; ++kt) {
      float4 v0 = *(const float4*)(xrow + kt * 32);
      float4 v1 = *(const float4*)(xrow + kt * 32 + 4);
      short8 a;
      a[0]=f2bf(v0.x); a[1]=f2bf(v0.y); a[2]=f2bf(v0.z); a[3]=f2bf(v0.w);
      a[4]=f2bf(v1.x); a[5]=f2bf(v1.y); a[6]=f2bf(v1.z); a[7]=f2bf(v1.w);
      afr[kt] = a;
    }
  }

  for (int s = 0; s < 16; ++s) {
    __syncthreads();
    {
      const int c  = tid & 63;
      const int o0 = tid >> 6;
      for (int oct = o0; oct < 32; oct += 4) {
        short8 w;
        #pragma unroll
        for (int j = 0; j < 8; ++j)
          w[j] = f2bf(Win[(size_t)(oct * 8 + j) * LATENT + s * 64 + c]);
        *(short8*)&lB[(oct * 64 + c) * 8] = w;
      }
    }
    __syncthreads();
    #pragma unroll
    for (int nt = 0; nt < 4; ++nt) {
      floatx4 acc0 = {0.f,0.f,0.f,0.f}, acc1 = {0.f,0.f,0.f,0.f};
      #pragma unroll
      for (int kt = 0; kt < 8; kt += 2) {
        short8 b0 = *(const short8*)&lB[(( kt   *4 + q) * 64 + nt*16 + ln) * 8];
        short8 b1 = *(const short8*)&lB[(((kt+1)*4 + q) * 64 + nt*16 + ln) * 8];
        acc0 = __builtin_amdgcn_mfma_f32_16x16x32_bf16(afr[kt],   b0, acc0, 0,0,0);
        acc1 = __builtin_amdgcn_mfma_f32_16x16x32_bf16(afr[kt+1], b1, acc1, 0,0,0);
      }
      floatx4 acc = acc0 + acc1;
      const int col = s*64 + nt*16 + ln;
      const float bv = bin[col];
      #pragma unroll
      for (int i = 0; i < 4; ++i) {
        int r = m0 + wave*16 + q*4 + i;       // flat row = b*SEQT + t
        int t = r & (SEQT - 1);
        int b = r >> 9;
        out[((size_t)t * BATCH + b) * LATENT + col] = acc[i] + bv;
      }
    }
  }
}

// ---------------------------------------------------------------------------
// Kernel 2: persistent recurrence, XCD-local sync.
// Group = physical XCD (read HW_REG_XCC_ID, claim slot via startup atomicAdd).
// Exactly 64 wgs/XCD (512 wgs at 2/CU x 32 CU/XCD, guaranteed by capacity).
// Per step: plain h stores (write-through L1 -> XCD L2), __syncthreads
// (drains vmcnt), one plain byte-store arrival into a per-(g,t) 64B line,
// peers poll + read ring with L1-bypassing AGENT relaxed loads (L2-served).
// No atomic RMW per step, no buffer_wbl2/inv — nothing leaves the XCD.
// ---------------------------------------------------------------------------
__global__ __launch_bounds__(256) void rnn_persistent(
    float* __restrict__ out, const float* __restrict__ Win,
    unsigned short* __restrict__ ring, unsigned char* __restrict__ flags,
    int* __restrict__ wcnt)
{
  __shared__ short lW[128 * 16 * 8];   // [(kt*4+q)][n][j], 32 KB
  __shared__ float red[4][16][16];     // 4 KB
  __shared__ int s_g, s_wid, s_bad;

  const int tid  = threadIdx.x;
  const int wave = tid >> 6;
  const int lane = tid & 63;
  const int q    = lane >> 4;
  const int ln   = lane & 15;

  if (tid == 0) {
    unsigned xcc;
    asm volatile("s_getreg_b32 %0, hwreg(HW_REG_XCC_ID)" : "=s"(xcc));
    xcc &= 7u;
    s_g   = (int)xcc;
    s_wid = atomicAdd(&wcnt[xcc], 1) & 63;   // within-XCD slot 0..63
    s_bad = 0;
  }
  __syncthreads();
  const int g    = s_g;
  const int wid  = s_wid;
  const int col0 = wid * 16;
  const int row0 = g * 16;
  unsigned char* fl = flags + (size_t)g * (SEQT * 64);

  // Stage Wh[:, col0..col0+16) (rows DIM.. of W_in) swizzled to bf16.
  for (int i = tid; i < 128 * 16; i += 256) {   // i = oct*16 + n ; k = oct*8+j
    const int oct = i >> 4, n = i & 15;
    short8 w;
    #pragma unroll
    for (int j = 0; j < 8; ++j)
      w[j] = f2bf(Win[(size_t)(DIM + oct*8 + j) * LATENT + col0 + n]);
    *(short8*)&lW[i * 8] = w;
  }

  const int erow = tid >> 4, ecol = tid & 15;
  float* outp = out + (size_t)(row0 + erow) * LATENT + col0 + ecol;
  unsigned short* ringp = ring + (size_t)(row0 + erow) * LATENT + col0 + ecol;
  __syncthreads();

  for (int t = 0; t < SEQT; ++t) {
    // xw prefetch (owner-exclusive location, plain load)
    float xw = outp[(size_t)t * (BATCH * LATENT)];
    float hsum = 0.f;
    if (t > 0) {
      // ---- wait for all 64 peer flags of step t-1 (one 64B line) ----
      const unsigned char* fbase = fl + (size_t)(t - 1) * 64;
      int guard = s_bad ? 1 : 4000000;
      for (;;) {
        unsigned v = __hip_atomic_load((const unsigned char*)(fbase + lane),
                                       __ATOMIC_RELAXED,
                                       __HIP_MEMORY_SCOPE_AGENT);
        if (__all(v != 0)) break;
        if (--guard <= 0) { s_bad = 1; break; }   // terminate, don't hang
      }

      // ---- ring read: rows row0+ln, this wave's K range, L1-bypassing ----
      const unsigned short* rbase =
          ring + ((size_t)((t - 1) & 3) * BATCH + row0 + ln) * LATENT
               + wave * 256 + q * 8;
      short8 a[8];
      #pragma unroll
      for (int kk = 0; kk < 8; ++kk) {
        union { u64 w[2]; short8 s; } u;
        u.w[0] = __hip_atomic_load((const u64*)(rbase + kk * 32),
                                   __ATOMIC_RELAXED, __HIP_MEMORY_SCOPE_AGENT);
        u.w[1] = __hip_atomic_load((const u64*)(rbase + kk * 32 + 4),
                                   __ATOMIC_RELAXED, __HIP_MEMORY_SCOPE_AGENT);
        a[kk] = u.s;
      }

      floatx4 acc0 = {0.f,0.f,0.f,0.f}, acc1 = {0.f,0.f,0.f,0.f};
      #pragma unroll
      for (int kk = 0; kk < 4; ++kk) {
        const int kt  = wave * 8 + kk;
        const int kt2 = wave * 8 + 4 + kk;
        short8 b  = *(const short8*)&lW[((kt  * 4 + q) * 16 + ln) * 8];
        short8 b2 = *(const short8*)&lW[((kt2 * 4 + q) * 16 + ln) * 8];
        acc0 = __builtin_amdgcn_mfma_f32_16x16x32_bf16(a[kk],     b,  acc0, 0,0,0);
        acc1 = __builtin_amdgcn_mfma_f32_16x16x32_bf16(a[4 + kk], b2, acc1, 0,0,0);
      }
      floatx4 acc = acc0 + acc1;
      #pragma unroll
      for (int i = 0; i < 4; ++i) red[wave][q*4 + i][ln] = acc[i];
      __syncthreads();
      hsum = red[0][erow][ecol] + red[1][erow][ecol]
           + red[2][erow][ecol] + red[3][erow][ecol];
    }

    const float h = tanhf(xw + hsum);
    outp [(size_t)t      * (BATCH * LATENT)] = h;                        // fp32 output
    ringp[(size_t)(t & 3) * (BATCH * LATENT)] = (unsigned short)f2bf(h); // bf16 ring (write-through -> L2)
    __syncthreads();   // drains all waves' stores (vmcnt(0) before s_barrier)
    if (tid == 0)
      *(volatile unsigned char*)(fl + (size_t)t * 64 + wid) = (unsigned char)1;
  }
}

// ---------------------------------------------------------------------------
extern "C" void kernel_launch(void* const* d_in, const int* in_sizes, int n_in,
                              void* d_out, int out_size, void* d_ws, size_t ws_size,
                              hipStream_t stream) {
  (void)in_sizes; (void)n_in; (void)out_size; (void)ws_size;
  const float* x   = (const float*)d_in[0];
  const float* Win = (const float*)d_in[1];
  const float* bin = (const float*)d_in[2];
  float* out = (float*)d_out;

  // ws layout: [0,32) per-XCD slot counters | [4096, +256K) flags | ring 1MB
  int*            wcnt  = (int*)d_ws;
  unsigned char*  flags = (unsigned char*)d_ws + 4096;
  unsigned short* ring  = (unsigned short*)((char*)d_ws + 4096 + 8 * SEQT * 64);

  hipMemsetAsync(d_ws, 0, 4096 + 8 * SEQT * 64, stream);
  xw_gemm<<<dim3(65536 / 64), dim3(256), 0, stream>>>(x, Win, bin, out);

  void* args[] = { &out, &Win, &ring, &flags, &wcnt };
  hipLaunchCooperativeKernel((void*)rnn_persistent, dim3(512), dim3(256),
                             args, 0, stream);
}